// Round 4
// baseline (984.402 us; speedup 1.0000x reference)
//
#include <hip/hip_runtime.h>
#include <math.h>

// BinaryTreeLSTM on MI355X — single persistent kernel (R4).
// Everything (weight shuffle, embs->bf16, bias5, leaf, 13 tree levels) runs
// in ONE kernel with manual grid barriers. Grid = 512 blocks = 2 blocks/CU
// (co-residency guaranteed: __launch_bounds__(256,2) caps VGPR<=256, LDS=0).
//
// Math identical to R3: h_prev (B,512) = [lh|rh] => one GEMM per level
// G = h_view @ [Wl|Wr]^T + bias5 (bias5 folds pad_xg; pad chunk 2 feeds both
// lf,rf). MFMA 16x16x32 bf16, fp32 acc; c fp32 end-to-end, h bf16.
// Weight frag f=((kc*16+grp)*NG+g): elem[lane*8+j]=W[k=kc*32+(lane>>4)*8+j]
// [n=g*256+grp*16+(lane&15)] -> b_frag load = coalesced 16B/lane dwordx4.
// Task map: tile = t & (tiles-1), grp = t >> ts -> consecutive waves (same
// block) share grp => b_frags L1-dedup, adjacent A tiles.

#define MEM 256
#define NBLK 512
#define NWAVE (NBLK * 4)

typedef __attribute__((ext_vector_type(8))) short bf16x8;
typedef __attribute__((ext_vector_type(4))) float f32x4;

__device__ __forceinline__ float sigf(float x) { return 1.0f / (1.0f + __expf(-x)); }

__device__ __forceinline__ unsigned short f2b(float f) {
  unsigned int u = __float_as_uint(f);
  u = (u + 0x7FFFu + ((u >> 16) & 1u)) >> 16;
  return (unsigned short)u;
}

// Sense-reversing grid barrier. Release fence (L2 writeback) before arrive,
// acquire fence (L2/L1 inv) after release — cross-XCD ping-pong buffers can
// be stale in a reader XCD's L2 from two levels ago.
__device__ __forceinline__ void gridbar(unsigned* cnt, unsigned* gen) {
  __syncthreads();
  if (threadIdx.x == 0) {
    __threadfence();  // release
    unsigned g = __hip_atomic_load(gen, __ATOMIC_RELAXED, __HIP_MEMORY_SCOPE_AGENT);
    unsigned a = __hip_atomic_fetch_add(cnt, 1u, __ATOMIC_ACQ_REL, __HIP_MEMORY_SCOPE_AGENT);
    if (a == NBLK - 1) {
      __hip_atomic_store(cnt, 0u, __ATOMIC_RELAXED, __HIP_MEMORY_SCOPE_AGENT);
      __hip_atomic_store(gen, g + 1u, __ATOMIC_RELEASE, __HIP_MEMORY_SCOPE_AGENT);
    } else {
      while (__hip_atomic_load(gen, __ATOMIC_RELAXED, __HIP_MEMORY_SCOPE_AGENT) == g)
        __builtin_amdgcn_s_sleep(2);
    }
    __threadfence();  // acquire
  }
  __syncthreads();
}

__global__ __launch_bounds__(256, 2) void k_tree(
    const float* embs, const float* Wx, const float* bx,
    const float* Wl, const float* Wr, const float* emb_last,
    unsigned short* Wcf, unsigned short* Wxf, unsigned short* eb,
    float* bias5, float* cA, float* cB, unsigned short* hA, unsigned short* hB,
    float* out, unsigned* cnt, unsigned* gen) {
  const int tid = threadIdx.x;
  const int lane = tid & 63;
  const int wave = tid >> 6;
  const int wave_id = blockIdx.x * 4 + wave;
  const int gtid = blockIdx.x * 256 + tid;  // 0..131071
  const int m = lane & 15, quad = lane >> 4;

  // ---------------- Phase 0: prep (grid-stride) ----------------
  for (int idx = gtid; idx < 1280 * 512; idx += NBLK * 256) {  // Wcf
    int f = idx >> 9, r = idx & 511;
    int l8 = r >> 3, j = r & 7;
    int gate = f % 5, t = f / 5;
    int grp = t & 15, kc = t >> 4;
    int k = kc * 32 + ((l8 >> 4) << 3) + j;
    int n = gate * 256 + (grp << 4) + (l8 & 15);
    float v = (k < 256) ? Wl[n * 256 + k] : Wr[n * 256 + (k - 256)];
    Wcf[idx] = f2b(v);
  }
  for (int idx = gtid; idx < 480 * 512; idx += NBLK * 256) {  // Wxf
    int f = idx >> 9, r = idx & 511;
    int l8 = r >> 3, j = r & 7;
    int gate = f % 3, t = f / 3;
    int grp = t & 15, kc = t >> 4;
    int k = kc * 32 + ((l8 >> 4) << 3) + j;
    const int gmap[3] = {0, 1, 3};
    int n = gmap[gate] * 256 + (grp << 4) + (l8 & 15);
    float v = (k < 300) ? Wx[n * 300 + k] : 0.0f;
    Wxf[idx] = f2b(v);
  }
  for (int idx = gtid; idx < 8192 * 320; idx += NBLK * 256) {  // embs->bf16 pad
    int row = idx / 320;
    int k = idx - row * 320;
    eb[idx] = (k < 300) ? f2b(embs[row * 300 + k]) : (unsigned short)0;
  }
  if (gtid < 1280) {  // bias5 = pad_xg (gate-mapped) with bx folded
    const int map5[5] = {0, 1, 2, 2, 3};
    int g = gtid >> 8, j = gtid & 255;
    int wrow = map5[g] * 256 + j;
    const float* w = Wx + wrow * 300;
    float s = bx[wrow];
    for (int k = 0; k < 300; k++) s += emb_last[k] * w[k];
    bias5[gtid] = s;
  }
  gridbar(cnt, gen);

  // ---------------- Phase 1: leaf (8192 tasks = 512 tiles x 16 grps) -------
  for (int t = wave_id; t < 8192; t += NWAVE) {
    int tile = t & 511;
    int grp = t >> 9;
    int row_a = tile * 16 + m;
    f32x4 acc0 = {0.f, 0.f, 0.f, 0.f}, acc1 = acc0, acc2 = acc0;
    const unsigned short* arow = eb + row_a * 320 + quad * 8;
#pragma unroll
    for (int kc = 0; kc < 10; kc++) {
      bf16x8 a = *(const bf16x8*)(arow + kc * 32);
      const unsigned short* bp = Wxf + ((kc * 16 + grp) * 3) * 512 + lane * 8;
      bf16x8 b0 = *(const bf16x8*)(bp);
      bf16x8 b1 = *(const bf16x8*)(bp + 512);
      bf16x8 b2 = *(const bf16x8*)(bp + 1024);
      acc0 = __builtin_amdgcn_mfma_f32_16x16x32_bf16(a, b0, acc0, 0, 0, 0);
      acc1 = __builtin_amdgcn_mfma_f32_16x16x32_bf16(a, b1, acc1, 0, 0, 0);
      acc2 = __builtin_amdgcn_mfma_f32_16x16x32_bf16(a, b2, acc2, 0, 0, 0);
    }
    int col = grp * 16 + m;
    float b0 = bx[col], b1 = bx[256 + col], b3 = bx[768 + col];
#pragma unroll
    for (int reg = 0; reg < 4; reg++) {
      int row = tile * 16 + quad * 4 + reg;
      float u = tanhf(acc0[reg] + b0);
      float ig = sigf(acc1[reg] + b1);
      float o = sigf(acc2[reg] + b3);
      float c = ig * u;
      cA[row * MEM + col] = c;
      hA[row * MEM + col] = f2b(o * tanhf(c));
    }
  }
  gridbar(cnt, gen);

  // ---------------- Phase 2: 13 tree levels ----------------
  const float* cs = cA;
  const unsigned short* hs = hA;
  int B = 4096;
  int ts = 8;  // log2(tiles)
  int lvl = 0;
  const bf16x8 zz = {0, 0, 0, 0, 0, 0, 0, 0};
  while (B >= 1) {
    float* dc;
    unsigned short* dh;
    bool last = (B == 1);
    if (last) {
      dc = out;
      dh = hB;  // dummy sink
    } else if ((lvl & 1) == 0) {
      dc = cB; dh = hB;
    } else {
      dc = cA; dh = hA;
    }
    int tiles = 1 << ts;
    int ntask = tiles * 16;
    for (int t = wave_id; t < ntask; t += NWAVE) {
      int tile = t & (tiles - 1);
      int grp = t >> ts;
      int row_a = tile * 16 + m;
      bool a_ok = (row_a < B);
      f32x4 acc0 = {0.f, 0.f, 0.f, 0.f}, acc1 = acc0, acc2 = acc0,
            acc3 = acc0, acc4 = acc0;
      const unsigned short* arow = hs + row_a * 512 + quad * 8;
#pragma unroll
      for (int kc = 0; kc < 16; kc++) {
        bf16x8 a = a_ok ? *(const bf16x8*)(arow + kc * 32) : zz;
        const unsigned short* bp = Wcf + ((kc * 16 + grp) * 5) * 512 + lane * 8;
        bf16x8 b0 = *(const bf16x8*)(bp);
        bf16x8 b1 = *(const bf16x8*)(bp + 512);
        bf16x8 b2 = *(const bf16x8*)(bp + 1024);
        bf16x8 b3 = *(const bf16x8*)(bp + 1536);
        bf16x8 b4 = *(const bf16x8*)(bp + 2048);
        acc0 = __builtin_amdgcn_mfma_f32_16x16x32_bf16(a, b0, acc0, 0, 0, 0);
        acc1 = __builtin_amdgcn_mfma_f32_16x16x32_bf16(a, b1, acc1, 0, 0, 0);
        acc2 = __builtin_amdgcn_mfma_f32_16x16x32_bf16(a, b2, acc2, 0, 0, 0);
        acc3 = __builtin_amdgcn_mfma_f32_16x16x32_bf16(a, b3, acc3, 0, 0, 0);
        acc4 = __builtin_amdgcn_mfma_f32_16x16x32_bf16(a, b4, acc4, 0, 0, 0);
      }
      int col = grp * 16 + m;
      float b0 = bias5[col], b1 = bias5[256 + col], b2 = bias5[512 + col];
      float b3 = bias5[768 + col], b4 = bias5[1024 + col];
#pragma unroll
      for (int reg = 0; reg < 4; reg++) {
        int row = tile * 16 + quad * 4 + reg;
        if (row >= B) continue;
        float u = tanhf(acc0[reg] + b0);
        float ig = sigf(acc1[reg] + b1);
        float lf = sigf(acc2[reg] + b2);
        float rf = sigf(acc3[reg] + b3);
        float o = sigf(acc4[reg] + b4);
        float lc = cs[(2 * row) * MEM + col];
        float rc = cs[(2 * row + 1) * MEM + col];
        float c = ig * u + lf * lc + rf * rc;
        float h = o * tanhf(c);
        dc[row * MEM + col] = c;
        dh[row * MEM + col] = f2b(h);
        if (last) out[256 + col] = h;
      }
    }
    cs = dc;
    hs = dh;
    B >>= 1;
    if (ts > 0) ts--;
    lvl++;
    if (B >= 1) gridbar(cnt, gen);
  }
}

extern "C" void kernel_launch(void* const* d_in, const int* in_sizes, int n_in,
                              void* d_out, int out_size, void* d_ws, size_t ws_size,
                              hipStream_t stream) {
  const float* embs = (const float*)d_in[0];
  const float* Wx = (const float*)d_in[1];
  const float* bx = (const float*)d_in[2];
  const float* Wl = (const float*)d_in[3];
  const float* Wr = (const float*)d_in[4];
  const float* emb_table = (const float*)d_in[5];
  float* out = (float*)d_out;

  // Workspace layout: [0,256B) barrier vars; then arrays (~25 MB total)
  unsigned* cnt = (unsigned*)d_ws;
  unsigned* gen = cnt + 1;
  float* base = (float*)((char*)d_ws + 256);
  float* cA = base;                              // 8192*256 f32
  float* cB = cA + 8192 * 256;                   // 4096*256 f32
  float* bias5 = cB + 4096 * 256;                // 1280 f32
  unsigned short* hA = (unsigned short*)(bias5 + 1280);  // 8192*256 bf16
  unsigned short* hB = hA + 8192 * 256;                  // 4096*256 bf16
  unsigned short* Wcf = hB + 4096 * 256;                 // 1280*512
  unsigned short* Wxf = Wcf + 1280 * 512;                // 480*512
  unsigned short* eb = Wxf + 480 * 512;                  // 8192*320

  hipMemsetAsync(d_ws, 0, 256, stream);  // reset barrier (ws is 0xAA-poisoned)

  k_tree<<<NBLK, 256, 0, stream>>>(
      embs, Wx, bx, Wl, Wr, emb_table + (in_sizes[5] - 300),
      Wcf, Wxf, eb, bias5, cA, cB, hA, hB, out, cnt, gen);
}

// Round 5
// 385.247 us; speedup vs baseline: 2.5552x; 2.5552x over previous
//
#include <hip/hip_runtime.h>
#include <math.h>

// BinaryTreeLSTM on MI355X — persistent kernel, contention-free barrier (R5).
// R4 post-mortem: 512 serialized cross-XCD atomic RMWs per barrier = ~60us
// per barrier. R5: per-block arrival flag on its OWN 128B line (parallel
// stores), block 0 polls all flags in parallel (1 flag/thread), publishes
// one `gen` word. Blocks with no remaining work post flag=0xFFFF and exit.
//
// Math identical to R3/R4: h_prev (B,512) = [lh|rh] => one GEMM per level
// G = h_view @ [Wl|Wr]^T + bias5 (bias5 folds pad_xg; pad chunk 2 feeds both
// lf,rf). MFMA 16x16x32 bf16, fp32 acc; c fp32 end-to-end, h bf16.
// Weight frag f=((kc*16+grp)*NG+g): elem[lane*8+j]=W[k=kc*32+(lane>>4)*8+j]
// [n=g*256+grp*16+(lane&15)] -> b_frag load = coalesced 16B/lane dwordx4.
// 256 blocks x 512 threads (8 waves): block's waves share grp => L1 dedup.

#define MEM 256
#define NBLK 256
#define NTHR 512
#define NWAVE (NBLK * 8)

typedef __attribute__((ext_vector_type(8))) short bf16x8;
typedef __attribute__((ext_vector_type(4))) float f32x4;

__device__ __forceinline__ float sigf(float x) { return 1.0f / (1.0f + __expf(-x)); }

__device__ __forceinline__ unsigned short f2b(float f) {
  unsigned int u = __float_as_uint(f);
  u = (u + 0x7FFFu + ((u >> 16) & 1u)) >> 16;
  return (unsigned short)u;
}

// Flag barrier. flags[b*32]: block b's arrival line. gen: broadcast word.
// Monotone targets 1,2,3,... (flags+gen memset to 0 before launch).
// done=true: post 0xFFFF (passes all future barriers) and skip the wait.
__device__ __forceinline__ void gridbar(unsigned* flags, unsigned* gen,
                                        unsigned target, bool done) {
  __syncthreads();
  if (blockIdx.x == 0) {
    if (threadIdx.x == 0) __threadfence();  // release block 0's data
    if (threadIdx.x < NBLK - 1) {
      unsigned b = threadIdx.x + 1;  // poll blocks 1..255, one per thread
      while (__hip_atomic_load(flags + b * 32, __ATOMIC_RELAXED,
                               __HIP_MEMORY_SCOPE_AGENT) < target)
        __builtin_amdgcn_s_sleep(1);
    }
    __syncthreads();  // all flags observed
    if (threadIdx.x == 0) {
      __hip_atomic_store(gen, target, __ATOMIC_RELEASE, __HIP_MEMORY_SCOPE_AGENT);
      __threadfence();  // acquire for block 0's subsequent reads
    }
    __syncthreads();
  } else {
    if (threadIdx.x == 0) {
      __threadfence();  // release: push this block's writes to L3
      __hip_atomic_store(flags + blockIdx.x * 32, done ? 0xFFFFu : target,
                         __ATOMIC_RELAXED, __HIP_MEMORY_SCOPE_AGENT);
      if (!done) {
        while (__hip_atomic_load(gen, __ATOMIC_RELAXED,
                                 __HIP_MEMORY_SCOPE_AGENT) < target)
          __builtin_amdgcn_s_sleep(1);
        __threadfence();  // acquire: invalidate stale L1/L2
      }
    }
    __syncthreads();
  }
}

__global__ __launch_bounds__(NTHR, 1) void k_tree(
    const float* embs, const float* Wx, const float* bx,
    const float* Wl, const float* Wr, const float* emb_last,
    unsigned short* Wcf, unsigned short* Wxf, unsigned short* eb,
    float* bias5, float* cA, float* cB, unsigned short* hA, unsigned short* hB,
    float* out, unsigned* flags, unsigned* gen) {
  const int tid = threadIdx.x;
  const int lane = tid & 63;
  const int wave = tid >> 6;
  const int wave_id = blockIdx.x * 8 + wave;
  const int gtid = blockIdx.x * NTHR + tid;  // 0..131071
  const int m = lane & 15, quad = lane >> 4;
  unsigned target = 0;

  // ---------------- Phase 0: prep (grid-stride) ----------------
  for (int idx = gtid; idx < 1280 * 512; idx += NBLK * NTHR) {  // Wcf
    int f = idx >> 9, r = idx & 511;
    int l8 = r >> 3, j = r & 7;
    int gate = f % 5, t = f / 5;
    int grp = t & 15, kc = t >> 4;
    int k = kc * 32 + ((l8 >> 4) << 3) + j;
    int n = gate * 256 + (grp << 4) + (l8 & 15);
    float v = (k < 256) ? Wl[n * 256 + k] : Wr[n * 256 + (k - 256)];
    Wcf[idx] = f2b(v);
  }
  for (int idx = gtid; idx < 480 * 512; idx += NBLK * NTHR) {  // Wxf
    int f = idx >> 9, r = idx & 511;
    int l8 = r >> 3, j = r & 7;
    int gate = f % 3, t = f / 3;
    int grp = t & 15, kc = t >> 4;
    int k = kc * 32 + ((l8 >> 4) << 3) + j;
    const int gmap[3] = {0, 1, 3};
    int n = gmap[gate] * 256 + (grp << 4) + (l8 & 15);
    float v = (k < 300) ? Wx[n * 300 + k] : 0.0f;
    Wxf[idx] = f2b(v);
  }
  for (int idx = gtid; idx < 8192 * 320; idx += NBLK * NTHR) {  // embs->bf16
    int row = idx / 320;
    int k = idx - row * 320;
    eb[idx] = (k < 300) ? f2b(embs[row * 300 + k]) : (unsigned short)0;
  }
  if (gtid < 1280) {  // bias5 = pad_xg (gate-mapped) with bx folded
    const int map5[5] = {0, 1, 2, 2, 3};
    int g = gtid >> 8, j = gtid & 255;
    int wrow = map5[g] * 256 + j;
    const float* w = Wx + wrow * 300;
    float s = bx[wrow];
    for (int k = 0; k < 300; k++) s += emb_last[k] * w[k];
    bias5[gtid] = s;
  }
  gridbar(flags, gen, ++target, false);

  // ---------------- Phase 1: leaf (8192 tasks = 512 tiles x 16 grps) -------
  for (int t = wave_id; t < 8192; t += NWAVE) {
    int tile = t & 511;
    int grp = t >> 9;
    int row_a = tile * 16 + m;
    f32x4 acc0 = {0.f, 0.f, 0.f, 0.f}, acc1 = acc0, acc2 = acc0;
    const unsigned short* arow = eb + row_a * 320 + quad * 8;
#pragma unroll
    for (int kc = 0; kc < 10; kc++) {
      bf16x8 a = *(const bf16x8*)(arow + kc * 32);
      const unsigned short* bp = Wxf + ((kc * 16 + grp) * 3) * 512 + lane * 8;
      bf16x8 b0 = *(const bf16x8*)(bp);
      bf16x8 b1 = *(const bf16x8*)(bp + 512);
      bf16x8 b2 = *(const bf16x8*)(bp + 1024);
      acc0 = __builtin_amdgcn_mfma_f32_16x16x32_bf16(a, b0, acc0, 0, 0, 0);
      acc1 = __builtin_amdgcn_mfma_f32_16x16x32_bf16(a, b1, acc1, 0, 0, 0);
      acc2 = __builtin_amdgcn_mfma_f32_16x16x32_bf16(a, b2, acc2, 0, 0, 0);
    }
    int col = grp * 16 + m;
    float b0 = bx[col], b1 = bx[256 + col], b3 = bx[768 + col];
#pragma unroll
    for (int reg = 0; reg < 4; reg++) {
      int row = tile * 16 + quad * 4 + reg;
      float u = tanhf(acc0[reg] + b0);
      float ig = sigf(acc1[reg] + b1);
      float o = sigf(acc2[reg] + b3);
      float c = ig * u;
      cA[row * MEM + col] = c;
      hA[row * MEM + col] = f2b(o * tanhf(c));
    }
  }
  gridbar(flags, gen, ++target, false);

  // ---------------- Phase 2: 13 tree levels ----------------
  const float* cs = cA;
  const unsigned short* hs = hA;
  int B = 4096;
  int ts = 8;  // log2(tiles)
  int lvl = 0;
  const bf16x8 zz = {0, 0, 0, 0, 0, 0, 0, 0};
  while (B >= 1) {
    float* dc;
    unsigned short* dh;
    bool last = (B == 1);
    if (last) {
      dc = out;
      dh = hB;  // dummy sink
    } else if ((lvl & 1) == 0) {
      dc = cB; dh = hB;
    } else {
      dc = cA; dh = hA;
    }
    int tiles = 1 << ts;
    int ntask = tiles * 16;
    for (int t = wave_id; t < ntask; t += NWAVE) {
      int tile = t & (tiles - 1);
      int grp = t >> ts;
      int row_a = tile * 16 + m;
      bool a_ok = (row_a < B);
      f32x4 acc0 = {0.f, 0.f, 0.f, 0.f}, acc1 = acc0, acc2 = acc0,
            acc3 = acc0, acc4 = acc0;
      const unsigned short* arow = hs + row_a * 512 + quad * 8;
#pragma unroll
      for (int kc = 0; kc < 16; kc++) {
        bf16x8 a = a_ok ? *(const bf16x8*)(arow + kc * 32) : zz;
        const unsigned short* bp = Wcf + ((kc * 16 + grp) * 5) * 512 + lane * 8;
        bf16x8 b0 = *(const bf16x8*)(bp);
        bf16x8 b1 = *(const bf16x8*)(bp + 512);
        bf16x8 b2 = *(const bf16x8*)(bp + 1024);
        bf16x8 b3 = *(const bf16x8*)(bp + 1536);
        bf16x8 b4 = *(const bf16x8*)(bp + 2048);
        acc0 = __builtin_amdgcn_mfma_f32_16x16x32_bf16(a, b0, acc0, 0, 0, 0);
        acc1 = __builtin_amdgcn_mfma_f32_16x16x32_bf16(a, b1, acc1, 0, 0, 0);
        acc2 = __builtin_amdgcn_mfma_f32_16x16x32_bf16(a, b2, acc2, 0, 0, 0);
        acc3 = __builtin_amdgcn_mfma_f32_16x16x32_bf16(a, b3, acc3, 0, 0, 0);
        acc4 = __builtin_amdgcn_mfma_f32_16x16x32_bf16(a, b4, acc4, 0, 0, 0);
      }
      int col = grp * 16 + m;
      float b0 = bias5[col], b1 = bias5[256 + col], b2 = bias5[512 + col];
      float b3 = bias5[768 + col], b4 = bias5[1024 + col];
#pragma unroll
      for (int reg = 0; reg < 4; reg++) {
        int row = tile * 16 + quad * 4 + reg;
        if (row >= B) continue;
        float u = tanhf(acc0[reg] + b0);
        float ig = sigf(acc1[reg] + b1);
        float lf = sigf(acc2[reg] + b2);
        float rf = sigf(acc3[reg] + b3);
        float o = sigf(acc4[reg] + b4);
        float lc = cs[(2 * row) * MEM + col];
        float rc = cs[(2 * row + 1) * MEM + col];
        float c = ig * u + lf * lc + rf * rc;
        float h = o * tanhf(c);
        dc[row * MEM + col] = c;
        dh[row * MEM + col] = f2b(h);
        if (last) out[256 + col] = h;
      }
    }
    cs = dc;
    hs = dh;
    B >>= 1;
    if (ts > 0) ts--;
    lvl++;
    if (B >= 1) {
      // Block has no tasks in any remaining level (future max ntask = max(B,16))
      int fut = (B > 16) ? B : 16;
      bool done = (blockIdx.x > 0) && (blockIdx.x * 8 >= fut);
      gridbar(flags, gen, ++target, done);
      if (done) return;
    }
  }
}

extern "C" void kernel_launch(void* const* d_in, const int* in_sizes, int n_in,
                              void* d_out, int out_size, void* d_ws, size_t ws_size,
                              hipStream_t stream) {
  const float* embs = (const float*)d_in[0];
  const float* Wx = (const float*)d_in[1];
  const float* bx = (const float*)d_in[2];
  const float* Wl = (const float*)d_in[3];
  const float* Wr = (const float*)d_in[4];
  const float* emb_table = (const float*)d_in[5];
  float* out = (float*)d_out;

  // Workspace: [0,4) gen | [128, 128+256*128) flags | data from 64KB (~25MB)
  unsigned* gen = (unsigned*)d_ws;
  unsigned* flags = (unsigned*)((char*)d_ws + 128);
  float* base = (float*)((char*)d_ws + 65536);
  float* cA = base;                              // 8192*256 f32
  float* cB = cA + 8192 * 256;                   // 4096*256 f32
  float* bias5 = cB + 4096 * 256;                // 1280 f32
  unsigned short* hA = (unsigned short*)(bias5 + 1280);  // 8192*256 bf16
  unsigned short* hB = hA + 8192 * 256;                  // 4096*256 bf16
  unsigned short* Wcf = hB + 4096 * 256;                 // 1280*512
  unsigned short* Wxf = Wcf + 1280 * 512;                // 480*512
  unsigned short* eb = Wxf + 480 * 512;                  // 8192*320

  hipMemsetAsync(d_ws, 0, 65536, stream);  // zero gen+flags (ws is poisoned)

  k_tree<<<NBLK, NTHR, 0, stream>>>(
      embs, Wx, bx, Wl, Wr, emb_table + (in_sizes[5] - 300),
      Wcf, Wxf, eb, bias5, cA, cB, hA, hB, out, flags, gen);
}